// Round 1
// baseline (329.929 us; speedup 1.0000x reference)
//
#include <hip/hip_runtime.h>

typedef __attribute__((ext_vector_type(8))) short bf16x8;
typedef __attribute__((ext_vector_type(4))) float f32x4;
typedef __attribute__((ext_vector_type(4))) unsigned int u32x4;
typedef __attribute__((ext_vector_type(8))) unsigned short ushort8;

#define BB 4
#define SS 2048
#define DD 512
#define HH 8
#define DKK 64
#define WWIN 16
#define MTOT (BB*SS)                 /* 8192 */
#define MKE  ((long)MTOT*DD)         /* 4,194,304 elems */
#define NKE  ((long)DD*DD)           /* 262,144 elems */

__device__ __forceinline__ unsigned short f2bf(float f) {
  unsigned int u = __float_as_uint(f);
  u += 0x7fffu + ((u >> 16) & 1u);
  return (unsigned short)(u >> 16);
}
__device__ __forceinline__ float bf2f(unsigned short s) {
  return __uint_as_float(((unsigned int)s) << 16);
}

__device__ __forceinline__ void gload_lds16(const unsigned short* g, unsigned short* l) {
  __builtin_amdgcn_global_load_lds((const __attribute__((address_space(1))) void*)g,
                                   (__attribute__((address_space(3))) void*)l, 16, 0, 0);
}

// ---------------- convert X (q,k,v fp32 -> bf16) + gather biases ----------------
__global__ __launch_bounds__(256) void convert_x(
    const float* __restrict__ q, const float* __restrict__ k, const float* __restrict__ v,
    const float* __restrict__ bq, const float* __restrict__ bk, const float* __restrict__ bv,
    unsigned short* __restrict__ xbf, float* __restrict__ bias_all)
{
  long idx = (long)blockIdx.x * 256 + threadIdx.x;
  if (idx < 3*DD) {
    bias_all[idx] = idx < DD ? bq[idx] : (idx < 2*DD ? bk[idx-DD] : bv[idx-2*DD]);
  }
  long e = idx * 8;                      // 8 elems per thread
  const long SZ = MKE;
  const float* s; long t = e;
  if (t < SZ) { s = q; }
  else if (t < 2*SZ) { s = k; t -= SZ; }
  else { s = v; t -= 2*SZ; }
  float4 a  = *(const float4*)(s + t);
  float4 b2 = *(const float4*)(s + t + 4);
  ushort8 o;
  o[0]=f2bf(a.x);  o[1]=f2bf(a.y);  o[2]=f2bf(a.z);  o[3]=f2bf(a.w);
  o[4]=f2bf(b2.x); o[5]=f2bf(b2.y); o[6]=f2bf(b2.z); o[7]=f2bf(b2.w);
  *(ushort8*)(xbf + e) = o;
}

// ---------------- transpose+convert weights: Wt[n][k] = bf16(W[k][n]) ----------------
__global__ __launch_bounds__(256) void convert_w(
    const float* __restrict__ Wq, const float* __restrict__ Wk,
    const float* __restrict__ Wv, const float* __restrict__ Wo,
    unsigned short* __restrict__ wt)
{
  int bx = blockIdx.x;                   // 0..255 : 4 matrices x 64 tiles
  int wm = bx >> 6;
  int tile = bx & 63;
  int tr = tile >> 3, tc = tile & 7;     // 8x8 tiles of 64x64
  const float* src = wm==0 ? Wq : wm==1 ? Wk : wm==2 ? Wv : Wo;
  unsigned short* dst = wt + (long)wm*NKE;
  __shared__ float tl[64][65];
  int t = threadIdx.x;
  int cr = t >> 6;                       // 0..3
  int cc = t & 63;
  for (int p = 0; p < 16; ++p) {
    int row = p*4 + cr;
    tl[row][cc] = src[(long)(tr*64+row)*DD + tc*64 + cc];
  }
  __syncthreads();
  for (int p = 0; p < 16; ++p) {
    int orow = p*4 + cr;                 // output row = original col
    dst[(long)(tc*64 + orow)*DD + tr*64 + cc] = f2bf(tl[cc][orow]);
  }
}

// ---------------- bf16 MFMA GEMM: C[M,N] = A[M,K] @ Bt[N,K]^T + bias ----------------
// 128x128 tile, BK=64, 4 waves (2x2), 4x4 x (16x16x32) fragments per wave.
template<int OUT_BF16>
__global__ __launch_bounds__(256, 2) void gemm_kernel(
    const unsigned short* __restrict__ Abase, long aZ,
    const unsigned short* __restrict__ Btbase, long bZ,
    const float* __restrict__ biasBase, long biasZ,
    void* __restrict__ outBase, long outZ,
    int M, int N, int K)
{
  const int z = blockIdx.z;
  const unsigned short* A  = Abase  + (long)z*aZ;
  const unsigned short* Bt = Btbase + (long)z*bZ;
  const float* bias = biasBase + (long)z*biasZ;

  const int tid  = threadIdx.x;
  const int lane = tid & 63;
  const int w    = tid >> 6;           // 0..3
  const int wr   = w >> 1, wc = w & 1;
  const int m0   = blockIdx.y * 128;
  const int n0   = blockIdx.x * 128;

  __shared__ unsigned short lA[128*64];
  __shared__ unsigned short lB[128*64];

  f32x4 acc[4][4] = {};

  for (int kt = 0; kt < K; kt += 64) {
    // stage 128x64 A-tile and 128x64 Bt-tile (16B per lane per issue)
    for (int i = 0; i < 4; ++i) {
      int e   = (w*4+i)*512 + lane*8;      // elem offset within tile
      int row = e >> 6, col = e & 63;
      gload_lds16(A  + (long)(m0 + row)*K + kt + col, &lA[(w*4+i)*512]);
      gload_lds16(Bt + (long)(n0 + row)*K + kt + col, &lB[(w*4+i)*512]);
    }
    __syncthreads();   // drains vmcnt before barrier (compiler-inserted)
    for (int kk = 0; kk < 2; ++kk) {
      bf16x8 af[4], bfr[4];
      for (int m = 0; m < 4; ++m) {
        int row = wr*64 + m*16 + (lane & 15);
        af[m] = *reinterpret_cast<const bf16x8*>(&lA[row*64 + kk*32 + (lane>>4)*8]);
      }
      for (int n = 0; n < 4; ++n) {
        int col = wc*64 + n*16 + (lane & 15);
        bfr[n] = *reinterpret_cast<const bf16x8*>(&lB[col*64 + kk*32 + (lane>>4)*8]);
      }
      for (int m = 0; m < 4; ++m)
        for (int n = 0; n < 4; ++n)
          acc[m][n] = __builtin_amdgcn_mfma_f32_16x16x32_bf16(af[m], bfr[n], acc[m][n], 0, 0, 0);
    }
    __syncthreads();
  }

  // epilogue: C/D layout col=lane&15, row=(lane>>4)*4+reg
  for (int m = 0; m < 4; ++m) {
    int rbase = m0 + wr*64 + m*16 + ((lane>>4)<<2);
    for (int n = 0; n < 4; ++n) {
      int col = n0 + wc*64 + n*16 + (lane & 15);
      float bv = bias[col];
      for (int r = 0; r < 4; ++r) {
        float val = acc[m][n][r] + bv;
        long idx = (long)z*outZ + (long)(rbase + r)*N + col;
        if (OUT_BF16) ((unsigned short*)outBase)[idx] = f2bf(val);
        else          ((float*)outBase)[idx] = val;
      }
    }
  }
}

// ---------------- banded local attention (window +-16), online softmax ----------------
// grid: (S/32, H, B); block 256 = 4 waves x 8 queries; lane = dk
__global__ __launch_bounds__(256) void attn_kernel(
    const unsigned short* __restrict__ Qbf, const unsigned short* __restrict__ Kbf,
    const unsigned short* __restrict__ Vbf, unsigned short* __restrict__ ctxbf)
{
  const int q0 = blockIdx.x * 32;
  const int h  = blockIdx.y;
  const int b  = blockIdx.z;
  const int tid = threadIdx.x, lane = tid & 63, w = tid >> 6;
  const int w0 = q0 - WWIN;             // window base (may be negative)

  __shared__ unsigned short Kl[64*64];
  __shared__ unsigned short Vl[64*64];

  const long baseRow = (long)b*SS*DD + (long)h*DKK;   // + row*DD

  // stage 64 rows x 64 dk of K and V (zero-fill out-of-range rows)
  for (int ii = 0; ii < 2; ++ii) {
    int u   = ii*256 + tid;             // 0..511 (16B units)
    int row = u >> 3, c8 = (u & 7) * 8;
    int g   = w0 + row;
    u32x4 kv = {0,0,0,0}, vv = {0,0,0,0};
    if (g >= 0 && g < SS) {
      kv = *(const u32x4*)(Kbf + baseRow + (long)g*DD + c8);
      vv = *(const u32x4*)(Vbf + baseRow + (long)g*DD + c8);
    }
    *(u32x4*)(Kl + row*64 + c8) = kv;
    *(u32x4*)(Vl + row*64 + c8) = vv;
  }
  __syncthreads();

  const float scale = 0.125f;           // 1/sqrt(64)
  for (int qi = 0; qi < 8; ++qi) {
    int q = q0 + w*8 + qi;
    float Qv = bf2f(Qbf[baseRow + (long)q*DD + lane]);
    float m = -INFINITY, den = 0.f, ctx = 0.f;
    for (int j = 0; j < 2*WWIN + 1; ++j) {
      int kq = q - WWIN + j;
      if (kq < 0 || kq >= SS) continue;        // wave-uniform branch
      int lr = (q - q0) + j;                   // 0..63
      float prod = Qv * bf2f(Kl[lr*64 + lane]);
      for (int off = 32; off; off >>= 1) prod += __shfl_xor(prod, off, 64);
      float s = prod * scale;
      float mn = fmaxf(m, s);
      float c = __expf(m - mn), p = __expf(s - mn);
      den = den * c + p;
      ctx = ctx * c + p * bf2f(Vl[lr*64 + lane]);
      m = mn;
    }
    ctxbf[baseRow + (long)q*DD + lane] = f2bf(ctx / den);
  }
}

extern "C" void kernel_launch(void* const* d_in, const int* in_sizes, int n_in,
                              void* d_out, int out_size, void* d_ws, size_t ws_size,
                              hipStream_t stream) {
  const float* q  = (const float*)d_in[0];
  const float* k  = (const float*)d_in[1];
  const float* v  = (const float*)d_in[2];
  const float* Wq = (const float*)d_in[3];
  const float* bq = (const float*)d_in[4];
  const float* Wk = (const float*)d_in[5];
  const float* bk = (const float*)d_in[6];
  const float* Wv = (const float*)d_in[7];
  const float* bv = (const float*)d_in[8];
  const float* Wo = (const float*)d_in[9];
  const float* bo = (const float*)d_in[10];

  char* ws = (char*)d_ws;
  unsigned short* xbf   = (unsigned short*)(ws);                 // 3*MKE bf16 = 25,165,824 B
  unsigned short* wtbf  = (unsigned short*)(ws + 25165824);      // 4*NKE bf16 =  2,097,152 B
  float*          bias_all = (float*)(ws + 27262976);            // 6,144 B
  unsigned short* qkvbf = (unsigned short*)(ws + 27269120);      // 3*MKE bf16 = 25,165,824 B
  unsigned short* ctxbf = (unsigned short*)(ws + 52434944);      // MKE bf16   =  8,388,608 B

  convert_x<<<6144, 256, 0, stream>>>(q, k, v, bq, bk, bv, xbf, bias_all);
  convert_w<<<256, 256, 0, stream>>>(Wq, Wk, Wv, Wo, wtbf);
  gemm_kernel<1><<<dim3(4, 64, 3), 256, 0, stream>>>(
      xbf, MKE, wtbf, NKE, bias_all, DD,
      (void*)qkvbf, MKE, MTOT, DD, DD);
  attn_kernel<<<dim3(SS/32, HH, BB), 256, 0, stream>>>(
      qkvbf, qkvbf + MKE, qkvbf + 2*MKE, ctxbf);
  gemm_kernel<0><<<dim3(4, 64, 1), 256, 0, stream>>>(
      ctxbf, 0, wtbf + 3*NKE, 0, bo, 0,
      (void*)d_out, 0, MTOT, DD, DD);
}

// Round 2
// 158.775 us; speedup vs baseline: 2.0780x; 2.0780x over previous
//
#include <hip/hip_runtime.h>

typedef __attribute__((ext_vector_type(8))) short bf16x8;
typedef __attribute__((ext_vector_type(4))) float f32x4;
typedef __attribute__((ext_vector_type(4))) unsigned int u32x4;
typedef __attribute__((ext_vector_type(8))) unsigned short ushort8;

#define BB 4
#define SS 2048
#define DD 512
#define HH 8
#define DKK 64
#define WWIN 16
#define MTOT (BB*SS)                 /* 8192 */
#define MKE  ((long)MTOT*DD)         /* 4,194,304 elems */
#define NKE  ((long)DD*DD)           /* 262,144 elems */

__device__ __forceinline__ unsigned short f2bf(float f) {
  unsigned int u = __float_as_uint(f);
  u += 0x7fffu + ((u >> 16) & 1u);
  return (unsigned short)(u >> 16);
}
__device__ __forceinline__ float bf2f(unsigned short s) {
  return __uint_as_float(((unsigned int)s) << 16);
}

__device__ __forceinline__ void gload_lds16(const unsigned short* g, unsigned short* l) {
  __builtin_amdgcn_global_load_lds((const __attribute__((address_space(1))) void*)g,
                                   (__attribute__((address_space(3))) void*)l, 16, 0, 0);
}

// ---------------- convert X (q,k,v fp32 -> bf16) + gather biases ----------------
__global__ __launch_bounds__(256) void convert_x(
    const float* __restrict__ q, const float* __restrict__ k, const float* __restrict__ v,
    const float* __restrict__ bq, const float* __restrict__ bk, const float* __restrict__ bv,
    unsigned short* __restrict__ xbf, float* __restrict__ bias_all)
{
  long idx = (long)blockIdx.x * 256 + threadIdx.x;
  if (idx < 3*DD) {
    bias_all[idx] = idx < DD ? bq[idx] : (idx < 2*DD ? bk[idx-DD] : bv[idx-2*DD]);
  }
  long e = idx * 8;                      // 8 elems per thread
  const long SZ = MKE;
  const float* s; long t = e;
  if (t < SZ) { s = q; }
  else if (t < 2*SZ) { s = k; t -= SZ; }
  else { s = v; t -= 2*SZ; }
  float4 a  = *(const float4*)(s + t);
  float4 b2 = *(const float4*)(s + t + 4);
  ushort8 o;
  o[0]=f2bf(a.x);  o[1]=f2bf(a.y);  o[2]=f2bf(a.z);  o[3]=f2bf(a.w);
  o[4]=f2bf(b2.x); o[5]=f2bf(b2.y); o[6]=f2bf(b2.z); o[7]=f2bf(b2.w);
  *(ushort8*)(xbf + e) = o;
}

// ---------------- transpose+convert weights: Wt[n][k] = bf16(W[k][n]) ----------------
__global__ __launch_bounds__(256) void convert_w(
    const float* __restrict__ Wq, const float* __restrict__ Wk,
    const float* __restrict__ Wv, const float* __restrict__ Wo,
    unsigned short* __restrict__ wt)
{
  int bx = blockIdx.x;                   // 0..255 : 4 matrices x 64 tiles
  int wm = bx >> 6;
  int tile = bx & 63;
  int tr = tile >> 3, tc = tile & 7;     // 8x8 tiles of 64x64
  const float* src = wm==0 ? Wq : wm==1 ? Wk : wm==2 ? Wv : Wo;
  unsigned short* dst = wt + (long)wm*NKE;
  __shared__ float tl[64][65];
  int t = threadIdx.x;
  int cr = t >> 6;                       // 0..3
  int cc = t & 63;
  for (int p = 0; p < 16; ++p) {
    int row = p*4 + cr;
    tl[row][cc] = src[(long)(tr*64+row)*DD + tc*64 + cc];
  }
  __syncthreads();
  for (int p = 0; p < 16; ++p) {
    int orow = p*4 + cr;                 // output row = original col
    dst[(long)(tc*64 + orow)*DD + tr*64 + cc] = f2bf(tl[cc][orow]);
  }
}

// ---------------- bf16 MFMA GEMM: C[M,N] = A[M,K] @ Bt[N,K]^T + bias ----------------
// 128x128 tile, BK=64, 4 waves (2x2), 4x4 x (16x16x32) fragments per wave.
template<int OUT_BF16>
__global__ __launch_bounds__(256, 2) void gemm_kernel(
    const unsigned short* __restrict__ Abase, long aZ,
    const unsigned short* __restrict__ Btbase, long bZ,
    const float* __restrict__ biasBase, long biasZ,
    void* __restrict__ outBase, long outZ,
    int M, int N, int K)
{
  const int z = blockIdx.z;
  const unsigned short* A  = Abase  + (long)z*aZ;
  const unsigned short* Bt = Btbase + (long)z*bZ;
  const float* bias = biasBase + (long)z*biasZ;

  const int tid  = threadIdx.x;
  const int lane = tid & 63;
  const int w    = tid >> 6;           // 0..3
  const int wr   = w >> 1, wc = w & 1;
  const int m0   = blockIdx.y * 128;
  const int n0   = blockIdx.x * 128;

  __shared__ unsigned short lA[128*64];
  __shared__ unsigned short lB[128*64];

  f32x4 acc[4][4] = {};

  for (int kt = 0; kt < K; kt += 64) {
    // stage 128x64 A-tile and 128x64 Bt-tile (16B per lane per issue)
    for (int i = 0; i < 4; ++i) {
      int e   = (w*4+i)*512 + lane*8;      // elem offset within tile
      int row = e >> 6, col = e & 63;
      gload_lds16(A  + (long)(m0 + row)*K + kt + col, &lA[(w*4+i)*512]);
      gload_lds16(Bt + (long)(n0 + row)*K + kt + col, &lB[(w*4+i)*512]);
    }
    __syncthreads();   // drains vmcnt before barrier (compiler-inserted)
    for (int kk = 0; kk < 2; ++kk) {
      bf16x8 af[4], bfr[4];
      for (int m = 0; m < 4; ++m) {
        int row = wr*64 + m*16 + (lane & 15);
        af[m] = *reinterpret_cast<const bf16x8*>(&lA[row*64 + kk*32 + (lane>>4)*8]);
      }
      for (int n = 0; n < 4; ++n) {
        int col = wc*64 + n*16 + (lane & 15);
        bfr[n] = *reinterpret_cast<const bf16x8*>(&lB[col*64 + kk*32 + (lane>>4)*8]);
      }
      for (int m = 0; m < 4; ++m)
        for (int n = 0; n < 4; ++n)
          acc[m][n] = __builtin_amdgcn_mfma_f32_16x16x32_bf16(af[m], bfr[n], acc[m][n], 0, 0, 0);
    }
    __syncthreads();
  }

  // epilogue: C/D layout col=lane&15, row=(lane>>4)*4+reg
  for (int m = 0; m < 4; ++m) {
    int rbase = m0 + wr*64 + m*16 + ((lane>>4)<<2);
    for (int n = 0; n < 4; ++n) {
      int col = n0 + wc*64 + n*16 + (lane & 15);
      float bv = bias[col];
      for (int r = 0; r < 4; ++r) {
        float val = acc[m][n][r] + bv;
        long idx = (long)z*outZ + (long)(rbase + r)*N + col;
        if (OUT_BF16) ((unsigned short*)outBase)[idx] = f2bf(val);
        else          ((float*)outBase)[idx] = val;
      }
    }
  }
}

// ---------------- banded local attention via MFMA ----------------
// grid: (S/128, H, B); block 256 = 4 waves; wave w owns queries [q0+32w, q0+32w+32)
// K/V window staged: rows [q0-16, q0+144) = 160 rows x 64 dk (zero-filled OOB)
// Per wave: scores = Q(32x64) @ K^T -> mask band -> softmax -> P @ V(64x64)
#define KP 76   /* LDS row pad (elems): keeps hot ds_read <=2-way bank aliased */
#define PP 76
__global__ __launch_bounds__(256) void attn_kernel(
    const unsigned short* __restrict__ Qbf, const unsigned short* __restrict__ Kbf,
    const unsigned short* __restrict__ Vbf, unsigned short* __restrict__ ctxbf)
{
  const int q0 = blockIdx.x * 128;
  const int h  = blockIdx.y;
  const int b  = blockIdx.z;
  const int tid = threadIdx.x, lane = tid & 63, w = tid >> 6;
  const int c = lane & 15, g = lane >> 4;
  const int w0 = q0 - WWIN;               // staged window global start

  __shared__ unsigned short K_l[160*KP];
  __shared__ unsigned short V_l[160*KP];
  __shared__ unsigned short P_l[4][32*PP];

  const long baseRow = (long)b*SS*DD + (long)h*DKK;

  // stage K/V rows [w0, w0+160), zero-fill out-of-sequence rows
  for (int i = 0; i < 5; ++i) {
    int u = i*256 + tid;                  // 1280 chunks of 8 elems
    int row = u >> 3, c8 = (u & 7) * 8;
    int gk = w0 + row;
    u32x4 kv = {0,0,0,0}, vv = {0,0,0,0};
    if (gk >= 0 && gk < SS) {
      kv = *(const u32x4*)(Kbf + baseRow + (long)gk*DD + c8);
      vv = *(const u32x4*)(Vbf + baseRow + (long)gk*DD + c8);
    }
    *(u32x4*)(&K_l[row*KP + c8]) = kv;
    *(u32x4*)(&V_l[row*KP + c8]) = vv;
  }
  __syncthreads();

  const int qw0   = q0 + w*32;            // wave's first query
  const int kbase = w*32;                 // wave's key window start (staged row)

  // ---- QK^T: A = Q rows (global), B = K rows (LDS, contiguous) ----
  bf16x8 aq[2][2];
  for (int m = 0; m < 2; ++m)
    for (int kk = 0; kk < 2; ++kk)
      aq[m][kk] = *reinterpret_cast<const bf16x8*>(
          Qbf + baseRow + (long)(qw0 + m*16 + c)*DD + kk*32 + g*8);

  f32x4 accs[2][4] = {};
  for (int kk = 0; kk < 2; ++kk) {
    bf16x8 bk[4];
    for (int n = 0; n < 4; ++n)
      bk[n] = *reinterpret_cast<const bf16x8*>(&K_l[(kbase + n*16 + c)*KP + kk*32 + g*8]);
    for (int m = 0; m < 2; ++m)
      for (int n = 0; n < 4; ++n)
        accs[m][n] = __builtin_amdgcn_mfma_f32_16x16x32_bf16(aq[m][kk], bk[n], accs[m][n], 0, 0, 0);
  }

  // ---- band mask + row softmax (rows live in 16-lane xor groups) ----
  float pden[2][4];
  for (int m = 0; m < 2; ++m) {
    for (int r = 0; r < 4; ++r) {
      int qi = m*16 + g*4 + r;            // 0..31
      float sv[4];
      float mx = -INFINITY;
      for (int n = 0; n < 4; ++n) {
        int kr = n*16 + c;                // 0..63
        int d  = kr - qi;
        int kg = w0 + kbase + kr;         // global key index
        bool ok = (d >= 0) && (d <= 2*WWIN) && (kg >= 0) && (kg < SS);
        sv[n] = ok ? accs[m][n][r] * 0.125f : -INFINITY;
        mx = fmaxf(mx, sv[n]);
      }
      for (int off = 1; off < 16; off <<= 1) mx = fmaxf(mx, __shfl_xor(mx, off, 64));
      float sum = 0.f;
      for (int n = 0; n < 4; ++n) {
        float e = __expf(sv[n] - mx);     // exp(-inf)=0 on masked
        sum += e;
        P_l[w][(m*16 + g*4 + r)*PP + n*16 + c] = f2bf(e);
      }
      for (int off = 1; off < 16; off <<= 1) sum += __shfl_xor(sum, off, 64);
      pden[m][r] = sum;
    }
  }
  __syncthreads();

  // ---- PV: A = P (LDS), B = V (LDS, strided scalar gather) ----
  f32x4 acco[2][4] = {};
  for (int kk = 0; kk < 2; ++kk) {
    bf16x8 pa[2];
    for (int m = 0; m < 2; ++m)
      pa[m] = *reinterpret_cast<const bf16x8*>(&P_l[w][(m*16 + c)*PP + kk*32 + g*8]);
    bf16x8 bv[4];
    int kb = kbase + kk*32 + g*8;
    for (int n = 0; n < 4; ++n) {
      ushort8 t;
      for (int j = 0; j < 8; ++j) t[j] = V_l[(kb + j)*KP + n*16 + c];
      bv[n] = *reinterpret_cast<bf16x8*>(&t);
    }
    for (int m = 0; m < 2; ++m)
      for (int n = 0; n < 4; ++n)
        acco[m][n] = __builtin_amdgcn_mfma_f32_16x16x32_bf16(pa[m], bv[n], acco[m][n], 0, 0, 0);
  }

  // ---- normalize + write ctx (bf16) ----
  for (int m = 0; m < 2; ++m) {
    for (int r = 0; r < 4; ++r) {
      int q = qw0 + m*16 + g*4 + r;
      float inv = 1.f / pden[m][r];
      for (int n = 0; n < 4; ++n)
        ctxbf[baseRow + (long)q*DD + n*16 + c] = f2bf(acco[m][n][r] * inv);
    }
  }
}

extern "C" void kernel_launch(void* const* d_in, const int* in_sizes, int n_in,
                              void* d_out, int out_size, void* d_ws, size_t ws_size,
                              hipStream_t stream) {
  const float* q  = (const float*)d_in[0];
  const float* k  = (const float*)d_in[1];
  const float* v  = (const float*)d_in[2];
  const float* Wq = (const float*)d_in[3];
  const float* bq = (const float*)d_in[4];
  const float* Wk = (const float*)d_in[5];
  const float* bk = (const float*)d_in[6];
  const float* Wv = (const float*)d_in[7];
  const float* bv = (const float*)d_in[8];
  const float* Wo = (const float*)d_in[9];
  const float* bo = (const float*)d_in[10];

  char* ws = (char*)d_ws;
  unsigned short* xbf   = (unsigned short*)(ws);                 // 3*MKE bf16 = 25,165,824 B
  unsigned short* wtbf  = (unsigned short*)(ws + 25165824);      // 4*NKE bf16 =  2,097,152 B
  float*          bias_all = (float*)(ws + 27262976);            // 6,144 B
  unsigned short* qkvbf = (unsigned short*)(ws + 27269120);      // 3*MKE bf16 = 25,165,824 B
  unsigned short* ctxbf = (unsigned short*)(ws + 52434944);      // MKE bf16   =  8,388,608 B

  convert_x<<<6144, 256, 0, stream>>>(q, k, v, bq, bk, bv, xbf, bias_all);
  convert_w<<<256, 256, 0, stream>>>(Wq, Wk, Wv, Wo, wtbf);
  gemm_kernel<1><<<dim3(4, 64, 3), 256, 0, stream>>>(
      xbf, MKE, wtbf, NKE, bias_all, DD,
      (void*)qkvbf, MKE, MTOT, DD, DD);
  attn_kernel<<<dim3(SS/128, HH, BB), 256, 0, stream>>>(
      qkvbf, qkvbf + MKE, qkvbf + 2*MKE, ctxbf);
  gemm_kernel<0><<<dim3(4, 64, 1), 256, 0, stream>>>(
      ctxbf, 0, wtbf + 3*NKE, 0, bo, 0,
      (void*)d_out, 0, MTOT, DD, DD);
}